// Round 7
// baseline (249.723 us; speedup 1.0000x reference)
//
#include <hip/hip_runtime.h>
#include <hip/hip_bf16.h>
#include <cstdint>
#include <cstddef>

#define D 128           // feature dim
#define KNB 10          // NUM_NEIGHBORS
#define SENT 0x7FFFFFFF
#define SHIFT 8         // nodes per bucket = 256
#define NPB 256
#define T_BIN 256
#define EPB 4096        // edges per binning block
#define MAXNB 1024

typedef __attribute__((ext_vector_type(8))) short short8;   // MFMA A/B frag (8 bf16)
typedef __attribute__((ext_vector_type(4))) float floatx4;  // MFMA C/D frag

__device__ inline unsigned bf16_rne(float f) {
  unsigned u = __builtin_bit_cast(unsigned, f);
  return (u + 0x7FFFu + ((u >> 16) & 1u)) >> 16;
}

// ---------------------------------------------------------------------------
// k_init2: counts[0..NB)=0 and slots[0..S)=SENT in one launch
// ---------------------------------------------------------------------------
__global__ __launch_bounds__(256) void k_init2(int* __restrict__ counts, int NB,
                                               int* __restrict__ slots, int S) {
  int i = blockIdx.x * 256 + threadIdx.x;
  if (i < NB) counts[i] = 0;
  if (i < S) slots[i] = SENT;
}

// ---------------------------------------------------------------------------
// k_count_gemmY: blocks [0,blocks_bin) = LDS-histogram edge count;
// blocks [blocks_bin,..) = Y = X @ W^T tiles (bf16 MFMA, fp32 accum, bf16 out).
// Mean/linear commute: out = mean(x_i) W^T + b = mean(x_i W^T) + b, so the
// gather afterwards runs over Y and directly produces out — the aggbh
// round-trip and the standalone GEMM launch are gone.
// ---------------------------------------------------------------------------
#define GBN 128
#define LDK 136  // padded LDS row stride (ushorts)

__global__ __launch_bounds__(256) void k_count_gemmY(const int* __restrict__ row, int E,
                                                     int NB, int* __restrict__ counts,
                                                     int blocks_bin,
                                                     const float* __restrict__ x,
                                                     const float* __restrict__ Wm,
                                                     unsigned short* __restrict__ yh,
                                                     int N) {
  if ((int)blockIdx.x < blocks_bin) {
    __shared__ int hist[MAXNB];
    for (int i = threadIdx.x; i < NB; i += T_BIN) hist[i] = 0;
    __syncthreads();
    int e0 = blockIdx.x * EPB;
    for (int i = threadIdx.x; i < EPB; i += T_BIN) {
      int e = e0 + i;
      if (e < E) atomicAdd(&hist[row[e] >> SHIFT], 1);
    }
    __syncthreads();
    for (int i = threadIdx.x; i < NB; i += T_BIN)
      if (hist[i]) atomicAdd(&counts[i], hist[i]);
    return;
  }

  // ---- GEMM-Y tile: Y[n][o] = sum_k X[n][k] * W[o][k], bf16 in/out ----
  __shared__ unsigned short sX[GBN * LDK];
  __shared__ unsigned short sW[GBN * LDK];
  const int tid = threadIdx.x;
  const int n0 = ((int)blockIdx.x - blocks_bin) * GBN;

#pragma unroll
  for (int i = 0; i < 16; ++i) {
    int q = i * 256 + tid;
    int r = q >> 5;            // 0..127
    int c4 = q & 31;           // float4 index in row
    float4 xv = make_float4(0.f, 0.f, 0.f, 0.f);
    if (n0 + r < N)
      xv = reinterpret_cast<const float4*>(x + (size_t)(n0 + r) * D)[c4];
    ushort4 ux;
    ux.x = (unsigned short)bf16_rne(xv.x);
    ux.y = (unsigned short)bf16_rne(xv.y);
    ux.z = (unsigned short)bf16_rne(xv.z);
    ux.w = (unsigned short)bf16_rne(xv.w);
    *reinterpret_cast<ushort4*>(&sX[r * LDK + c4 * 4]) = ux;
    float4 wv = reinterpret_cast<const float4*>(Wm + (size_t)r * D)[c4];
    ushort4 uw;
    uw.x = (unsigned short)bf16_rne(wv.x);
    uw.y = (unsigned short)bf16_rne(wv.y);
    uw.z = (unsigned short)bf16_rne(wv.z);
    uw.w = (unsigned short)bf16_rne(wv.w);
    *reinterpret_cast<ushort4*>(&sW[r * LDK + c4 * 4]) = uw;
  }
  __syncthreads();

  const int wave = tid >> 6;
  const int lane = tid & 63;
  const int lrow = lane & 15;
  const int quad = lane >> 4;

  floatx4 acc[2][8];
#pragma unroll
  for (int mt = 0; mt < 2; ++mt)
#pragma unroll
    for (int nt = 0; nt < 8; ++nt)
      acc[mt][nt] = (floatx4){0.f, 0.f, 0.f, 0.f};

#pragma unroll
  for (int ks = 0; ks < 4; ++ks) {
    int koff = ks * 32 + quad * 8;
    short8 a0 = *reinterpret_cast<const short8*>(&sX[(wave * 32 + lrow) * LDK + koff]);
    short8 a1 = *reinterpret_cast<const short8*>(&sX[(wave * 32 + 16 + lrow) * LDK + koff]);
#pragma unroll
    for (int nt = 0; nt < 8; ++nt) {
      short8 b = *reinterpret_cast<const short8*>(&sW[(nt * 16 + lrow) * LDK + koff]);
      acc[0][nt] = __builtin_amdgcn_mfma_f32_16x16x32_bf16(a0, b, acc[0][nt], 0, 0, 0);
      acc[1][nt] = __builtin_amdgcn_mfma_f32_16x16x32_bf16(a1, b, acc[1][nt], 0, 0, 0);
    }
  }

  // C/D: col o = nt*16 + (lane&15), row = quad*4 + reg (HW-verified m89)
#pragma unroll
  for (int mt = 0; mt < 2; ++mt) {
    int rbase = n0 + wave * 32 + mt * 16 + quad * 4;
#pragma unroll
    for (int reg = 0; reg < 4; ++reg) {
      int r = rbase + reg;
      if (r < N) {
        unsigned short* op = yh + (size_t)r * D + lrow;
#pragma unroll
        for (int nt = 0; nt < 8; ++nt)
          op[nt * 16] = (unsigned short)bf16_rne(acc[mt][nt][reg]);
      }
    }
  }
}

// ---------------------------------------------------------------------------
__global__ __launch_bounds__(MAXNB) void k_scan(const int* __restrict__ counts, int NB,
                                                int* __restrict__ bases,
                                                int* __restrict__ cursor) {
  __shared__ int buf[MAXNB];
  int t = threadIdx.x;
  int v = (t < NB) ? counts[t] : 0;
  buf[t] = v;
  __syncthreads();
  for (int off = 1; off < MAXNB; off <<= 1) {
    int xv = (t >= off) ? buf[t - off] : 0;
    __syncthreads();
    buf[t] += xv;
    __syncthreads();
  }
  if (t < NB) {
    int base = buf[t] - v;
    bases[t] = base;
    cursor[t] = base;
  }
}

// ---------------------------------------------------------------------------
// bin edges into bucket regions; entry = (row&255)<<24 | edge_id (E < 2^24)
// ---------------------------------------------------------------------------
__global__ __launch_bounds__(T_BIN) void k_scatter2(const int* __restrict__ row, int E,
                                                    int NB, int* __restrict__ cursor,
                                                    unsigned* __restrict__ binned) {
  __shared__ int hist[MAXNB];
  __shared__ int lbase[MAXNB];
  for (int i = threadIdx.x; i < NB; i += T_BIN) hist[i] = 0;
  __syncthreads();
  int e0 = blockIdx.x * EPB;
  for (int i = threadIdx.x; i < EPB; i += T_BIN) {
    int e = e0 + i;
    if (e < E) atomicAdd(&hist[row[e] >> SHIFT], 1);
  }
  __syncthreads();
  for (int i = threadIdx.x; i < NB; i += T_BIN) {
    int h = hist[i];
    lbase[i] = h ? atomicAdd(&cursor[i], h) : 0;
  }
  __syncthreads();
  for (int i = threadIdx.x; i < NB; i += T_BIN) hist[i] = 0;  // reuse as cursor
  __syncthreads();
  for (int i = threadIdx.x; i < EPB; i += T_BIN) {
    int e = e0 + i;
    if (e < E) {
      int r = row[e];
      int b = r >> SHIFT;
      int pos = lbase[b] + atomicAdd(&hist[b], 1);
      binned[pos] = ((unsigned)(r & (NPB - 1)) << 24) | (unsigned)e;
    }
  }
}

// ---------------------------------------------------------------------------
// one WG per bucket: LDS atomicMin cascade -> 10 smallest edge ids per node
// ---------------------------------------------------------------------------
__global__ __launch_bounds__(256) void k_select(const unsigned* __restrict__ binned,
                                                const int* __restrict__ bases,
                                                const int* __restrict__ counts,
                                                int* __restrict__ slots_g, int N, int E) {
  __shared__ int sl[NPB * KNB];
  int b = blockIdx.x;
  int nbase = b << SHIFT;
  int nloc = min(NPB, N - nbase);
  for (int i = threadIdx.x; i < nloc * KNB; i += 256) sl[i] = SENT;
  __syncthreads();
  int base = bases[b];
  int cnt = counts[b];
  if (cnt > E) cnt = E;  // hardening
  for (int i = threadIdx.x; i < cnt; i += 256) {
    unsigned en = binned[base + i];
    int rl = (int)(en >> 24);
    int v = (int)(en & 0xFFFFFFu);
    int* s = &sl[rl * KNB];
#pragma unroll
    for (int k = 0; k < KNB; ++k) {
      int old = atomicMin(&s[k], v);
      if (old == SENT) break;
      v = v > old ? v : old;
    }
  }
  __syncthreads();
  for (int i = threadIdx.x; i < nloc * KNB; i += 256)
    slots_g[(size_t)nbase * KNB + i] = sl[i];
}

// ---------------------------------------------------------------------------
// k_aggY: out[n] = mean(Y[col_j]) + bias  (fp32 mean of bf16 Y rows).
// One wave per node; fixed-trip 10-load pipeline (R6-proven, gather wall
// ~3.5 TB/s of random-64B-line L2 fills served by L3).
// HARDENING (load-bearing, R3/R5 post-mortems): (unsigned)eid < E rejects
// SENT and poison-derived values; col range-checked before indexing yh.
// deg-0 fallback: out = Y[n] + bias (identical to bf16(x[n]) @ W + b path).
// ---------------------------------------------------------------------------
__global__ __launch_bounds__(256) void k_aggY(const unsigned* __restrict__ yh,
                                              const float* __restrict__ bias,
                                              const int* __restrict__ ei,
                                              const int* __restrict__ slots,
                                              float* __restrict__ out,
                                              int N, int E) {
  int wave = threadIdx.x >> 6;
  int lane = threadIdx.x & 63;
  int n = blockIdx.x * 4 + wave;
  if (n >= N) return;

  int eid = SENT;
  if (lane < KNB) eid = slots[(size_t)n * KNB + lane];
  bool valid = (lane < KNB) && ((unsigned)eid < (unsigned)E);
  int nsel = __popcll(__ballot(valid));
  int c = valid ? ei[(size_t)E + eid] : -1;

  unsigned uu[KNB];
  float wj[KNB];
#pragma unroll
  for (int j = 0; j < KNB; ++j) {
    int cj = __shfl(c, j);
    bool vj = (unsigned)cj < (unsigned)N;
    wj[j] = vj ? 1.f : 0.f;
    uu[j] = yh[(size_t)(vj ? cj : 0) * 64 + lane];  // 2 bf16: elems 2*lane, 2*lane+1
  }

  float2 bv = reinterpret_cast<const float2*>(bias)[lane];
  float ax, ay;
  if (nsel > 0) {
    ax = 0.f; ay = 0.f;
#pragma unroll
    for (int j = 0; j < KNB; ++j) {
      ax += wj[j] * __builtin_bit_cast(float, uu[j] << 16);
      ay += wj[j] * __builtin_bit_cast(float, uu[j] & 0xFFFF0000u);
    }
    float sc = 1.f / (float)nsel;
    ax = ax * sc + bv.x;
    ay = ay * sc + bv.y;
  } else {
    unsigned u = yh[(size_t)n * 64 + lane];
    ax = __builtin_bit_cast(float, u << 16) + bv.x;
    ay = __builtin_bit_cast(float, u & 0xFFFF0000u) + bv.y;
  }
  reinterpret_cast<float2*>(out + (size_t)n * D)[lane] = make_float2(ax, ay);
}

// ---------------------------------------------------------------------------
// fallback path (ws too small for yh): fp32 gather + fp32 VALU GEMM (R2-proven)
// ---------------------------------------------------------------------------
__global__ __launch_bounds__(256) void k_agg(const float* __restrict__ x,
                                             const int* __restrict__ ei,
                                             const int* __restrict__ slots,
                                             float* __restrict__ agg,
                                             int N, int E) {
  int wave = threadIdx.x >> 6;
  int lane = threadIdx.x & 63;
  int n = blockIdx.x * 4 + wave;
  if (n >= N) return;
  int eid = SENT;
  if (lane < KNB) eid = slots[(size_t)n * KNB + lane];
  bool valid = (lane < KNB) && ((unsigned)eid < (unsigned)E);
  unsigned long long m = __ballot(valid);
  int nsel = __popcll(m);
  int c = valid ? ei[(size_t)E + eid] : 0;
  float2 acc = make_float2(0.f, 0.f);
  if (nsel > 0) {
    unsigned long long mm = m;
    while (mm) {
      int j = (int)__builtin_ctzll(mm);
      mm &= mm - 1;
      int cj = __shfl(c, j);
      if ((unsigned)cj >= (unsigned)N) cj = 0;
      float2 v = reinterpret_cast<const float2*>(x + (size_t)cj * D)[lane];
      acc.x += v.x; acc.y += v.y;
    }
    float sc = 1.f / (float)nsel;
    acc.x *= sc; acc.y *= sc;
  } else {
    acc = reinterpret_cast<const float2*>(x + (size_t)n * D)[lane];
  }
  reinterpret_cast<float2*>(agg + (size_t)n * D)[lane] = acc;
}

#define BN 128
#define KC 32
#define LDP 132

__global__ __launch_bounds__(256) void k_gemm(const float* __restrict__ agg,
                                              const float* __restrict__ Wm,
                                              const float* __restrict__ bias,
                                              float* __restrict__ out, int N) {
  __shared__ float sA[KC][LDP];
  __shared__ float sW[KC][LDP];
  const int tid = threadIdx.x;
  const int tx = tid & 15;
  const int ty = tid >> 4;
  const int n0 = blockIdx.x * BN;

  float acc[8][8];
#pragma unroll
  for (int i = 0; i < 8; ++i)
#pragma unroll
    for (int j = 0; j < 8; ++j) acc[i][j] = 0.f;

  const int nl = tid >> 3;
  const int kq = tid & 7;

  for (int kc = 0; kc < D; kc += KC) {
#pragma unroll
    for (int i = 0; i < 4; ++i) {
      int rrow = nl + i * 32;
      int n = n0 + rrow;
      float4 av = make_float4(0.f, 0.f, 0.f, 0.f);
      if (n < N)
        av = reinterpret_cast<const float4*>(agg + (size_t)n * D + kc)[kq];
      int k = kq * 4;
      sA[k+0][rrow] = av.x; sA[k+1][rrow] = av.y;
      sA[k+2][rrow] = av.z; sA[k+3][rrow] = av.w;
      float4 wv = reinterpret_cast<const float4*>(Wm + (size_t)rrow * D + kc)[kq];
      sW[k+0][rrow] = wv.x; sW[k+1][rrow] = wv.y;
      sW[k+2][rrow] = wv.z; sW[k+3][rrow] = wv.w;
    }
    __syncthreads();
#pragma unroll
    for (int k = 0; k < KC; ++k) {
      float4 a0 = *reinterpret_cast<const float4*>(&sA[k][ty * 8]);
      float4 a1 = *reinterpret_cast<const float4*>(&sA[k][ty * 8 + 4]);
      float4 w0 = *reinterpret_cast<const float4*>(&sW[k][tx * 8]);
      float4 w1 = *reinterpret_cast<const float4*>(&sW[k][tx * 8 + 4]);
      float a[8] = {a0.x, a0.y, a0.z, a0.w, a1.x, a1.y, a1.z, a1.w};
      float w[8] = {w0.x, w0.y, w0.z, w0.w, w1.x, w1.y, w1.z, w1.w};
#pragma unroll
      for (int i = 0; i < 8; ++i)
#pragma unroll
        for (int j = 0; j < 8; ++j)
          acc[i][j] += a[i] * w[j];
    }
    __syncthreads();
  }

  float4 b0 = reinterpret_cast<const float4*>(bias)[tx * 2];
  float4 b1 = reinterpret_cast<const float4*>(bias)[tx * 2 + 1];
#pragma unroll
  for (int i = 0; i < 8; ++i) {
    int n = n0 + ty * 8 + i;
    if (n < N) {
      float4 v0 = make_float4(acc[i][0] + b0.x, acc[i][1] + b0.y,
                              acc[i][2] + b0.z, acc[i][3] + b0.w);
      float4 v1 = make_float4(acc[i][4] + b1.x, acc[i][5] + b1.y,
                              acc[i][6] + b1.z, acc[i][7] + b1.w);
      float4* op = reinterpret_cast<float4*>(out + (size_t)n * D + tx * 8);
      op[0] = v0;
      op[1] = v1;
    }
  }
}

// ---------------------------------------------------------------------------
extern "C" void kernel_launch(void* const* d_in, const int* in_sizes, int n_in,
                              void* d_out, int out_size, void* d_ws, size_t ws_size,
                              hipStream_t stream) {
  const float* x    = (const float*)d_in[0];
  const int*   ei   = (const int*)d_in[1];
  const float* Wm   = (const float*)d_in[2];
  const float* bias = (const float*)d_in[3];
  float* out = (float*)d_out;

  const int N = in_sizes[0] / D;
  const int E = in_sizes[1] / 2;
  const int NB = (N + NPB - 1) >> SHIFT;

  // ws layout: counts|bases|cursor | slots[N*10] | yh (N*256B bf16 Y=XW^T)
  int* counts = (int*)d_ws;
  int* bases  = counts + NB;
  int* cursor = bases + NB;
  size_t off_slots = ((size_t)(3 * NB) * 4 + 15) & ~(size_t)15;
  int* slots = (int*)((char*)d_ws + off_slots);
  size_t off_yh = (off_slots + (size_t)N * KNB * 4 + 15) & ~(size_t)15;
  unsigned short* yh = (unsigned short*)((char*)d_ws + off_yh);

  const bool have_yh = ws_size >= off_yh + (size_t)N * D * 2;

  unsigned* binned = (unsigned*)d_out;  // staged in d_out, dead after k_select
  const int blocks_bin = (E + EPB - 1) / EPB;
  const int S = N * KNB;
  const int gblocks = have_yh ? (N + GBN - 1) / GBN : 0;

  k_init2<<<(S + 255) / 256, 256, 0, stream>>>(counts, NB, slots, S);
  k_count_gemmY<<<blocks_bin + gblocks, T_BIN, 0, stream>>>(ei, E, NB, counts,
                                                            blocks_bin, x, Wm, yh, N);
  k_scan<<<1, MAXNB, 0, stream>>>(counts, NB, bases, cursor);
  k_scatter2<<<blocks_bin, T_BIN, 0, stream>>>(ei, E, NB, cursor, binned);
  k_select<<<NB, 256, 0, stream>>>(binned, bases, counts, slots, N, E);

  if (have_yh) {
    k_aggY<<<(N + 3) / 4, 256, 0, stream>>>((const unsigned*)yh, bias, ei, slots,
                                            out, N, E);
  } else {
    k_agg<<<(N + 3) / 4, 256, 0, stream>>>(x, ei, slots, out, N, E);
    k_gemm<<<(N + BN - 1) / BN, 256, 0, stream>>>(out, Wm, bias, out, N);
  }
}